// Round 17
// baseline (236.411 us; speedup 1.0000x reference)
//
#include <hip/hip_runtime.h>
#include <hip/hip_bf16.h>
#include <cstdint>
#include <cstddef>

typedef __attribute__((ext_vector_type(8))) __bf16 bf16x8;
typedef __attribute__((ext_vector_type(4))) float f32x4;
typedef __attribute__((ext_vector_type(16))) float f32x16;

#define MFMA16(a, b, c) __builtin_amdgcn_mfma_f32_16x16x32_bf16((a), (b), (c), 0, 0, 0)
#define MFMA32(a, b, c) __builtin_amdgcn_mfma_f32_32x32x16_bf16((a), (b), (c), 0, 0, 0)
#define MFMA8(a, b, c)  __builtin_amdgcn_mfma_f32_32x32x16_fp8_fp8((a), (b), (c), 0, 0, 0)

__device__ __forceinline__ f32x16 zf16() {
    f32x16 z;
    #pragma unroll
    for (int r = 0; r < 16; ++r) z[r] = 0.f;
    return z;
}

__device__ __forceinline__ void swap32(unsigned& a, unsigned& b) {
    asm("v_permlane32_swap_b32 %0, %1" : "+v"(a), "+v"(b));
}

// ---------------------------------------------------------------------------
// prep: blocks 0..511 = x -> x8T fp8 [2][256][4096] (transposed) + xrow bf16;
// 512..639 = VO transpose -> vot; 640..895 = Q/K weight cvt (Q scaled).
// ---------------------------------------------------------------------------
__global__ __launch_bounds__(256) void prep(const float* __restrict__ x,
                                            const float* __restrict__ Qw,
                                            const float* __restrict__ Kw,
                                            const float* __restrict__ VO,
                                            unsigned char* __restrict__ x8T,
                                            __bf16* __restrict__ xrow,
                                            __bf16* __restrict__ wb,
                                            __bf16* __restrict__ vot) {
    __shared__ float tile[64][65];
    const int bid = blockIdx.x;
    if (bid < 512) {
        const int b = bid >> 8;
        const int rem = bid & 255;
        const int tt = rem >> 2, dd = rem & 3;
        const int t0 = tt * 64, d0 = dd * 64;
        #pragma unroll
        for (int j = 0; j < 16; ++j) {
            int idx = j * 256 + threadIdx.x;
            int t = idx >> 6, d = idx & 63;
            float v = x[((size_t)(b * 4096 + t0 + t)) * 256 + d0 + d];
            tile[t][d] = v;
            xrow[((size_t)(b * 4096 + t0 + t)) * 256 + d0 + d] = (__bf16)v;
        }
        __syncthreads();
        #pragma unroll
        for (int j = 0; j < 8; ++j) {
            int idx = j * 256 + threadIdx.x;
            int d = idx >> 5, tp = idx & 31;      // d 0..63, t-pair 0..31
            float v0 = tile[tp * 2][d];
            float v1 = tile[tp * 2 + 1][d];
            int wpk = __builtin_amdgcn_cvt_pk_fp8_f32(v0, v1, 0, false);
            *(unsigned short*)(x8T + (size_t)(b * 256 + d0 + d) * 4096 + t0 + tp * 2) =
                (unsigned short)wpk;
        }
    } else if (bid < 640) {
        const int k = bid - 512;
        const int h = k >> 4;
        const int rem = k & 15;
        const int dt = rem >> 2, et = rem & 3;
        const int d0 = dt * 64, e0 = et * 64;
        #pragma unroll
        for (int j = 0; j < 16; ++j) {
            int idx = j * 256 + threadIdx.x;
            int d = idx >> 6, e = idx & 63;
            tile[d][e] = VO[((size_t)(h * 256 + d0 + d)) * 256 + e0 + e];
        }
        __syncthreads();
        #pragma unroll
        for (int j = 0; j < 16; ++j) {
            int idx = j * 256 + threadIdx.x;
            int e = idx >> 6, d = idx & 63;
            vot[((size_t)(e0 + e)) * 2048 + h * 256 + d0 + d] = (__bf16)tile[d][e];
        }
    } else {
        const float cl = 1.4426950408889634f / 16.0f;
        #pragma unroll
        for (int e = 0; e < 2; ++e) {
            int i = (bid - 640) * 512 + e * 256 + threadIdx.x;
            float v = (i < 65536) ? Qw[i] * cl : Kw[i - 65536];
            wb[i] = (__bf16)v;
        }
    }
}

// ---------------------------------------------------------------------------
// proj (round-8): block = 64 t-rows (4 waves x 16 rows); wave keeps its
// 16-row x A-fragments in registers, loops 16 (h,s) tasks (bf16 weights).
// ---------------------------------------------------------------------------
__global__ __launch_bounds__(256) void proj_kernel(const __bf16* __restrict__ xrow,
                                                   const __bf16* __restrict__ wb,
                                                   __bf16* __restrict__ qo,
                                                   __bf16* __restrict__ ko) {
    const int w = threadIdx.x >> 6;
    const int l = threadIdx.x & 63;
    const int g = l >> 4, c = l & 15;
    const int tg = blockIdx.x * 64 + w * 16;

    bf16x8 af[8];
    #pragma unroll
    for (int kk = 0; kk < 8; ++kk)
        af[kk] = *(const bf16x8*)(xrow + (size_t)(tg + c) * 256 + kk * 32 + g * 8);

    const int b = tg >> 12, t = tg & 4095;
    #pragma unroll
    for (int hs = 0; hs < 16; ++hs) {
        const int h = hs >> 1, s = hs & 1;
        const __bf16* W = wb + (size_t)(s * 8 + h) * 8192;  // [32][256]
        f32x4 acc0 = {0.f, 0.f, 0.f, 0.f}, acc1 = {0.f, 0.f, 0.f, 0.f};
        #pragma unroll
        for (int kk = 0; kk < 8; ++kk) {
            bf16x8 b0 = *(const bf16x8*)(W + (size_t)c * 256 + kk * 32 + g * 8);
            bf16x8 b1 = *(const bf16x8*)(W + (size_t)(16 + c) * 256 + kk * 32 + g * 8);
            acc0 = MFMA16(af[kk], b0, acc0);
            acc1 = MFMA16(af[kk], b1, acc1);
        }
        __bf16* outp = s ? ko : qo;
        const size_t obase = (size_t)(b * 8 + h) * 4096 + t;
        #pragma unroll
        for (int i = 0; i < 4; ++i) {
            outp[(obase + 4 * g + i) * 32 + c]      = (__bf16)acc0[i];
            outp[(obase + 4 * g + i) * 32 + 16 + c] = (__bf16)acc1[i];
        }
    }
}

// ---------------------------------------------------------------------------
// attn v15: round-14 per-wave algorithm (fp8 PV, 72B-padded tile, reg-staged,
// no-max softmax) but 4-wave blocks / 128 q-rows, grid 512 -> TWO independent
// barrier groups per CU. Regime check (rule #23): binder is now the serial
// QK->exp2->pack->PV chain (MFMA pipe only 52%), not LDS bandwidth -> phase
// diversity between the two blocks can overlap one block's VALU phase with
// the other's MFMA phase. Registers unchanged (2 waves/SIMD, ~248 peak).
// grid = 512 blocks x 256 threads (2 blocks/CU)
// ---------------------------------------------------------------------------

// P C-layout regs -> fp8 A-frag (8 x e4m3 across 2 dwords, halves swapped)
#define MK8FRAG(dst, V, base)                                                  \
    {                                                                          \
        unsigned d0 = 0, d1 = 0;                                               \
        d0 = __builtin_amdgcn_cvt_pk_fp8_f32(V[(base) + 0], V[(base) + 1], d0, false); \
        d0 = __builtin_amdgcn_cvt_pk_fp8_f32(V[(base) + 2], V[(base) + 3], d0, true);  \
        d1 = __builtin_amdgcn_cvt_pk_fp8_f32(V[(base) + 4], V[(base) + 5], d1, false); \
        d1 = __builtin_amdgcn_cvt_pk_fp8_f32(V[(base) + 6], V[(base) + 7], d1, true);  \
        swap32(d0, d1);                                                        \
        union { unsigned u[2]; long l; } z;                                    \
        z.u[0] = d0; z.u[1] = d1;                                              \
        dst = z.l;                                                             \
    }

__global__ __launch_bounds__(256, 2) void attn_kernel(const __bf16* __restrict__ qg,
                                                      const __bf16* __restrict__ kg,
                                                      const unsigned char* __restrict__ x8g,
                                                      __bf16* __restrict__ ctx) {
    // x-tile buffers: [256 d][72 B] (64B fp8 data + 8B pad) x2 + scales
    __shared__ __align__(16) unsigned char lds[2 * 18432 + 512];
    unsigned char* xbuf0 = lds;
    unsigned char* xbuf1 = lds + 18432;
    float* scale_base = (float*)(lds + 36864);

    const int bid = blockIdx.x;
    const int bh = bid >> 5;         // 16 (b,h) pairs
    const int tt = bid & 31;         // 32 t-chunks of 128
    const int b = bh >> 3, h = bh & 7;
    const int t0 = tt * 128;
    const int tid = threadIdx.x;     // 0..255
    const int w = tid >> 6;          // 0..3
    const int l = tid & 63;
    const int l31 = l & 31, hi = l >> 5;

    float* scale_w = scale_base + w * 32;

    const unsigned char* x8b = x8g + (size_t)b * 256 * 4096;
    const __bf16* kg_bh = kg + (size_t)bh * 4096 * 32;

    // staging geometry: thread covers one 64B d-row of the 16KB tile
    const int srow = tid;            // d row 0..255

    const size_t qoff = ((size_t)bh * 4096 + t0 + w * 32 + l31) * 32;
    const bf16x8 qf0 = *(const bf16x8*)(qg + qoff + hi * 8);
    const bf16x8 qf1 = *(const bf16x8*)(qg + qoff + 16 + hi * 8);

    f32x16 acc[8];
    #pragma unroll
    for (int n = 0; n < 8; ++n)
        #pragma unroll
        for (int r = 0; r < 16; ++r) acc[n][r] = 0.f;

    float lsum = 0.f;

    bf16x8 kA[2][2];
    #pragma unroll
    for (int s = 0; s < 2; ++s)
        #pragma unroll
        for (int st = 0; st < 2; ++st)
            kA[s][st] = *(const bf16x8*)(kg_bh + (size_t)(s * 32 + l31) * 32 + st * 16 + hi * 8);

    // prologue: stage tile 0 into xbuf0
    {
        const unsigned char* sp = x8b + (size_t)srow * 4096;
        uint4 la = *(const uint4*)sp;
        uint4 lb = *(const uint4*)(sp + 16);
        uint4 lc = *(const uint4*)(sp + 32);
        uint4 ld = *(const uint4*)(sp + 48);
        unsigned char* dp = xbuf0 + srow * 72;
        union { uint4 v; unsigned long long q[2]; } ua, ub, uc, ud;
        ua.v = la; ub.v = lb; uc.v = lc; ud.v = ld;
        ((unsigned long long*)dp)[0] = ua.q[0];
        ((unsigned long long*)dp)[1] = ua.q[1];
        ((unsigned long long*)(dp + 16))[0] = ub.q[0];
        ((unsigned long long*)(dp + 16))[1] = ub.q[1];
        ((unsigned long long*)(dp + 32))[0] = uc.q[0];
        ((unsigned long long*)(dp + 32))[1] = uc.q[1];
        ((unsigned long long*)(dp + 48))[0] = ud.q[0];
        ((unsigned long long*)(dp + 48))[1] = ud.q[1];
    }
    __syncthreads();

    for (int ut = 0; ut < 64; ++ut) {
        unsigned char* xcur = (ut & 1) ? xbuf1 : xbuf0;
        unsigned char* xnxt = (ut & 1) ? xbuf0 : xbuf1;

        // issue next-tile stage loads (wrap on last iter; write is harmless)
        const int u_next = ((ut + 1) & 63) * 64;
        const unsigned char* sp = x8b + (size_t)srow * 4096 + u_next;
        const uint4 la = *(const uint4*)sp;
        const uint4 lb = *(const uint4*)(sp + 16);
        const uint4 lc = *(const uint4*)(sp + 32);
        const uint4 ld = *(const uint4*)(sp + 48);

        // ---- S^T = K * Q^T (bf16, log2-domain, scale pre-folded in Q) ----
        f32x16 s0 = MFMA32(kA[0][0], qf0, zf16());
        s0 = MFMA32(kA[0][1], qf1, s0);
        f32x16 s1 = MFMA32(kA[1][0], qf0, zf16());
        s1 = MFMA32(kA[1][1], qf1, s1);

        if (ut < 63) {  // prefetch next k-tile fragments
            const __bf16* kp = kg_bh + (size_t)(ut + 1) * 64 * 32;
            #pragma unroll
            for (int s = 0; s < 2; ++s)
                #pragma unroll
                for (int st = 0; st < 2; ++st)
                    kA[s][st] = *(const bf16x8*)(kp + (size_t)(s * 32 + l31) * 32 + st * 16 + hi * 8);
        }

        // ---- P = exp2(S); no max subtraction (bounded scores) ----
        float rs = 0.f;
        #pragma unroll
        for (int r = 0; r < 16; ++r) {
            float p = __builtin_amdgcn_exp2f(s0[r]);
            s0[r] = p; rs += p;
        }
        #pragma unroll
        for (int r = 0; r < 16; ++r) {
            float p = __builtin_amdgcn_exp2f(s1[r]);
            s1[r] = p; rs += p;
        }
        lsum += rs;

        // ---- P -> fp8 A-frags ----
        long pf0, pf1, pf2, pf3;
        MK8FRAG(pf0, s0, 0);
        MK8FRAG(pf1, s0, 8);
        MK8FRAG(pf2, s1, 0);
        MK8FRAG(pf3, s1, 8);

        // ---- PV (fp8): acc[n] += P[q][u16] * x[u16][d-tile n] ----
        __builtin_amdgcn_s_setprio(1);
        #pragma unroll
        for (int kk = 0; kk < 4; ++kk) {
            const long pa = (kk == 0) ? pf0 : (kk == 1) ? pf1 : (kk == 2) ? pf2 : pf3;
            #pragma unroll
            for (int n = 0; n < 8; ++n) {
                const long xb = *(const long*)(xcur + (n * 32 + l31) * 72 + kk * 16 + hi * 8);
                acc[n] = MFMA8(pa, xb, acc[n]);
            }
        }
        __builtin_amdgcn_s_setprio(0);

        // ---- write staged tile (compiler inserts vmcnt wait here) ----
        {
            unsigned char* dp = xnxt + srow * 72;
            union { uint4 v; unsigned long long q[2]; } ua, ub, uc, ud;
            ua.v = la; ub.v = lb; uc.v = lc; ud.v = ld;
            ((unsigned long long*)dp)[0] = ua.q[0];
            ((unsigned long long*)dp)[1] = ua.q[1];
            ((unsigned long long*)(dp + 16))[0] = ub.q[0];
            ((unsigned long long*)(dp + 16))[1] = ub.q[1];
            ((unsigned long long*)(dp + 32))[0] = uc.q[0];
            ((unsigned long long*)(dp + 32))[1] = uc.q[1];
            ((unsigned long long*)(dp + 48))[0] = ud.q[0];
            ((unsigned long long*)(dp + 48))[1] = ud.q[1];
        }
        __syncthreads();
    }

    // ---- epilogue: combine lsum across lane halves, broadcast 1/lsum ----
    lsum += __shfl_xor(lsum, 32);
    const float linv = 1.0f / lsum;
    if (!hi) scale_w[l31] = linv;
    f32x4 iv[4];
    #pragma unroll
    for (int q4 = 0; q4 < 4; ++q4)
        iv[q4] = *(const f32x4*)&scale_w[q4 * 8 + hi * 4];
    #pragma unroll
    for (int n = 0; n < 8; ++n) {
        #pragma unroll
        for (int r = 0; r < 16; ++r) {
            int t = t0 + w * 32 + (r & 3) + 8 * (r >> 2) + 4 * hi;
            int d = n * 32 + l31;
            ctx[((size_t)(b * 4096 + t) * 8 + h) * 256 + d] =
                (__bf16)(acc[n][r] * iv[r >> 2][r & 3]);
        }
    }
}

// ---------------------------------------------------------------------------
// gemm_out (round-8): out[bt][e] = sum_k ctx[bt][k] * VOT[e][k].
// block = 64 m-rows x 128 e (4 waves; wave = 2 m-tiles x 32 e).
// ---------------------------------------------------------------------------
__global__ __launch_bounds__(256) void gemm_out(const __bf16* __restrict__ ctx,
                                                const __bf16* __restrict__ vot,
                                                float* __restrict__ out) {
    const int bid = blockIdx.x;
    const int mt2 = bid >> 1;
    const int eh = bid & 1;
    const int w = threadIdx.x >> 6;
    const int l = threadIdx.x & 63;
    const int l31 = l & 31, hi = l >> 5;
    const size_t a0row = (size_t)(mt2 * 64 + l31) * 2048;
    const size_t a1row = (size_t)(mt2 * 64 + 32 + l31) * 2048;
    const size_t brow  = (size_t)(eh * 128 + w * 32 + l31) * 2048;
    f32x16 acc0 = zf16(), acc1 = zf16();
    #pragma unroll 4
    for (int kk = 0; kk < 128; ++kk) {
        bf16x8 bfr = *(const bf16x8*)(vot + brow + kk * 16 + hi * 8);
        bf16x8 a0  = *(const bf16x8*)(ctx + a0row + kk * 16 + hi * 8);
        bf16x8 a1  = *(const bf16x8*)(ctx + a1row + kk * 16 + hi * 8);
        acc0 = MFMA32(a0, bfr, acc0);
        acc1 = MFMA32(a1, bfr, acc1);
    }
    const int e = eh * 128 + w * 32 + l31;
    #pragma unroll
    for (int r = 0; r < 16; ++r) {
        int crow = (r & 3) + 8 * (r >> 2) + 4 * hi;
        out[(size_t)(mt2 * 64 + crow) * 256 + e]      = acc0[r];
        out[(size_t)(mt2 * 64 + 32 + crow) * 256 + e] = acc1[r];
    }
}

// ---------------------------------------------------------------------------
extern "C" void kernel_launch(void* const* d_in, const int* in_sizes, int n_in,
                              void* d_out, int out_size, void* d_ws, size_t ws_size,
                              hipStream_t stream) {
    const float* x  = (const float*)d_in[0];  // [2][4096][256]
    const float* Qw = (const float*)d_in[1];  // [8][32][256]
    const float* Kw = (const float*)d_in[2];  // [8][32][256]
    const float* VO = (const float*)d_in[3];  // [8][256][256]
    float* out = (float*)d_out;               // [2][4096][256]

    char* ws = (char*)d_ws;
    unsigned char* x8 = (unsigned char*)(ws);              // 2 MB  [2][256][4096] fp8
    __bf16* xrow = (__bf16*)(ws + ((size_t)4 << 20));      // 4 MB  [2][4096][256]
    __bf16* qb   = (__bf16*)(ws + ((size_t)8 << 20));      // 4 MB  [2][8][4096][32]
    __bf16* kb   = (__bf16*)(ws + ((size_t)12 << 20));     // 4 MB
    __bf16* wb   = (__bf16*)(ws + ((size_t)16 << 20));     // 256 KB [2][8][32][256]
    __bf16* vot  = (__bf16*)(ws + ((size_t)17 << 20));     // 1 MB  [256][2048]
    __bf16* ctx  = (__bf16*)(ws + ((size_t)18 << 20));     // 32 MB [2][4096][8][256]

    prep<<<896, 256, 0, stream>>>(x, Qw, Kw, VO, x8, xrow, wb, vot);
    proj_kernel<<<128, 256, 0, stream>>>(xrow, wb, qb, kb);
    attn_kernel<<<512, 256, 0, stream>>>(qb, kb, x8, ctx);
    gemm_out<<<256, 256, 0, stream>>>(ctx, vot, out);
}

// Round 18
// 213.475 us; speedup vs baseline: 1.1074x; 1.1074x over previous
//
#include <hip/hip_runtime.h>
#include <hip/hip_bf16.h>
#include <cstdint>
#include <cstddef>

typedef __attribute__((ext_vector_type(8))) __bf16 bf16x8;
typedef __attribute__((ext_vector_type(4))) float f32x4;
typedef __attribute__((ext_vector_type(16))) float f32x16;

#define MFMA16(a, b, c) __builtin_amdgcn_mfma_f32_16x16x32_bf16((a), (b), (c), 0, 0, 0)
#define MFMA32(a, b, c) __builtin_amdgcn_mfma_f32_32x32x16_bf16((a), (b), (c), 0, 0, 0)
#define MFMA8(a, b, c)  __builtin_amdgcn_mfma_f32_32x32x16_fp8_fp8((a), (b), (c), 0, 0, 0)

__device__ __forceinline__ f32x16 zf16() {
    f32x16 z;
    #pragma unroll
    for (int r = 0; r < 16; ++r) z[r] = 0.f;
    return z;
}

__device__ __forceinline__ void swap32(unsigned& a, unsigned& b) {
    asm("v_permlane32_swap_b32 %0, %1" : "+v"(a), "+v"(b));
}

// ---------------------------------------------------------------------------
// prep: blocks 0..511 = x -> x8T fp8 [2][256][4096] (transposed) + xrow bf16;
// 512..639 = VO transpose -> vot; 640..895 = Q/K weight cvt (Q scaled).
// ---------------------------------------------------------------------------
__global__ __launch_bounds__(256) void prep(const float* __restrict__ x,
                                            const float* __restrict__ Qw,
                                            const float* __restrict__ Kw,
                                            const float* __restrict__ VO,
                                            unsigned char* __restrict__ x8T,
                                            __bf16* __restrict__ xrow,
                                            __bf16* __restrict__ wb,
                                            __bf16* __restrict__ vot) {
    __shared__ float tile[64][65];
    const int bid = blockIdx.x;
    if (bid < 512) {
        const int b = bid >> 8;
        const int rem = bid & 255;
        const int tt = rem >> 2, dd = rem & 3;
        const int t0 = tt * 64, d0 = dd * 64;
        #pragma unroll
        for (int j = 0; j < 16; ++j) {
            int idx = j * 256 + threadIdx.x;
            int t = idx >> 6, d = idx & 63;
            float v = x[((size_t)(b * 4096 + t0 + t)) * 256 + d0 + d];
            tile[t][d] = v;
            xrow[((size_t)(b * 4096 + t0 + t)) * 256 + d0 + d] = (__bf16)v;
        }
        __syncthreads();
        #pragma unroll
        for (int j = 0; j < 8; ++j) {
            int idx = j * 256 + threadIdx.x;
            int d = idx >> 5, tp = idx & 31;      // d 0..63, t-pair 0..31
            float v0 = tile[tp * 2][d];
            float v1 = tile[tp * 2 + 1][d];
            int wpk = __builtin_amdgcn_cvt_pk_fp8_f32(v0, v1, 0, false);
            *(unsigned short*)(x8T + (size_t)(b * 256 + d0 + d) * 4096 + t0 + tp * 2) =
                (unsigned short)wpk;
        }
    } else if (bid < 640) {
        const int k = bid - 512;
        const int h = k >> 4;
        const int rem = k & 15;
        const int dt = rem >> 2, et = rem & 3;
        const int d0 = dt * 64, e0 = et * 64;
        #pragma unroll
        for (int j = 0; j < 16; ++j) {
            int idx = j * 256 + threadIdx.x;
            int d = idx >> 6, e = idx & 63;
            tile[d][e] = VO[((size_t)(h * 256 + d0 + d)) * 256 + e0 + e];
        }
        __syncthreads();
        #pragma unroll
        for (int j = 0; j < 16; ++j) {
            int idx = j * 256 + threadIdx.x;
            int e = idx >> 6, d = idx & 63;
            vot[((size_t)(e0 + e)) * 2048 + h * 256 + d0 + d] = (__bf16)tile[d][e];
        }
    } else {
        const float cl = 1.4426950408889634f / 16.0f;
        #pragma unroll
        for (int e = 0; e < 2; ++e) {
            int i = (bid - 640) * 512 + e * 256 + threadIdx.x;
            float v = (i < 65536) ? Qw[i] * cl : Kw[i - 65536];
            wb[i] = (__bf16)v;
        }
    }
}

// ---------------------------------------------------------------------------
// proj (round-8): block = 64 t-rows (4 waves x 16 rows); wave keeps its
// 16-row x A-fragments in registers, loops 16 (h,s) tasks (bf16 weights).
// ---------------------------------------------------------------------------
__global__ __launch_bounds__(256) void proj_kernel(const __bf16* __restrict__ xrow,
                                                   const __bf16* __restrict__ wb,
                                                   __bf16* __restrict__ qo,
                                                   __bf16* __restrict__ ko) {
    const int w = threadIdx.x >> 6;
    const int l = threadIdx.x & 63;
    const int g = l >> 4, c = l & 15;
    const int tg = blockIdx.x * 64 + w * 16;

    bf16x8 af[8];
    #pragma unroll
    for (int kk = 0; kk < 8; ++kk)
        af[kk] = *(const bf16x8*)(xrow + (size_t)(tg + c) * 256 + kk * 32 + g * 8);

    const int b = tg >> 12, t = tg & 4095;
    #pragma unroll
    for (int hs = 0; hs < 16; ++hs) {
        const int h = hs >> 1, s = hs & 1;
        const __bf16* W = wb + (size_t)(s * 8 + h) * 8192;  // [32][256]
        f32x4 acc0 = {0.f, 0.f, 0.f, 0.f}, acc1 = {0.f, 0.f, 0.f, 0.f};
        #pragma unroll
        for (int kk = 0; kk < 8; ++kk) {
            bf16x8 b0 = *(const bf16x8*)(W + (size_t)c * 256 + kk * 32 + g * 8);
            bf16x8 b1 = *(const bf16x8*)(W + (size_t)(16 + c) * 256 + kk * 32 + g * 8);
            acc0 = MFMA16(af[kk], b0, acc0);
            acc1 = MFMA16(af[kk], b1, acc1);
        }
        __bf16* outp = s ? ko : qo;
        const size_t obase = (size_t)(b * 8 + h) * 4096 + t;
        #pragma unroll
        for (int i = 0; i < 4; ++i) {
            outp[(obase + 4 * g + i) * 32 + c]      = (__bf16)acc0[i];
            outp[(obase + 4 * g + i) * 32 + 16 + c] = (__bf16)acc1[i];
        }
    }
}

// ---------------------------------------------------------------------------
// attn v13 (best measured, rounds 14/16): v8 structure (8 waves, 32 q-rows/
// wave, 2 waves/SIMD, grid 256) with fp8 PV: P and x in e4m3,
// mfma_f32_32x32x16_fp8_fp8 (bf16 rate, half operand bytes) -> PV LDS reads
// halve (b64). x-tile [256d][64u] fp8, rows padded to 72B -> all LDS accesses
// 2-way-or-free. Reg-staged x (global->reg at loop top, ds_write after PV).
// QK stays bf16. No-max softmax. grid = 256 blocks x 512 threads (1 block/CU)
// ---------------------------------------------------------------------------

// P C-layout regs -> fp8 A-frag (8 x e4m3 across 2 dwords, halves swapped)
#define MK8FRAG(dst, V, base)                                                  \
    {                                                                          \
        unsigned d0 = 0, d1 = 0;                                               \
        d0 = __builtin_amdgcn_cvt_pk_fp8_f32(V[(base) + 0], V[(base) + 1], d0, false); \
        d0 = __builtin_amdgcn_cvt_pk_fp8_f32(V[(base) + 2], V[(base) + 3], d0, true);  \
        d1 = __builtin_amdgcn_cvt_pk_fp8_f32(V[(base) + 4], V[(base) + 5], d1, false); \
        d1 = __builtin_amdgcn_cvt_pk_fp8_f32(V[(base) + 6], V[(base) + 7], d1, true);  \
        swap32(d0, d1);                                                        \
        union { unsigned u[2]; long l; } z;                                    \
        z.u[0] = d0; z.u[1] = d1;                                              \
        dst = z.l;                                                             \
    }

__global__ __launch_bounds__(512, 2) void attn_kernel(const __bf16* __restrict__ qg,
                                                      const __bf16* __restrict__ kg,
                                                      const unsigned char* __restrict__ x8g,
                                                      __bf16* __restrict__ ctx) {
    // x-tile buffers: [256 d][72 B] (64B fp8 data + 8B pad) x2 + scales
    __shared__ __align__(16) unsigned char lds[2 * 18432 + 1024];
    unsigned char* xbuf0 = lds;
    unsigned char* xbuf1 = lds + 18432;
    float* scale_base = (float*)(lds + 36864);

    const int bid = blockIdx.x;
    const int bh = bid >> 4;
    const int tt = bid & 15;
    const int b = bh >> 3, h = bh & 7;
    const int t0 = tt * 256;
    const int tid = threadIdx.x;
    const int w = tid >> 6;
    const int l = tid & 63;
    const int l31 = l & 31, hi = l >> 5;

    float* scale_w = scale_base + w * 32;

    const unsigned char* x8b = x8g + (size_t)b * 256 * 4096;
    const __bf16* kg_bh = kg + (size_t)bh * 4096 * 32;

    // staging geometry: thread covers 32B of the 16KB tile
    const int srow = tid >> 1;            // d row 0..255
    const int soff = (tid & 1) * 32;      // byte offset within 64B row

    const size_t qoff = ((size_t)bh * 4096 + t0 + w * 32 + l31) * 32;
    const bf16x8 qf0 = *(const bf16x8*)(qg + qoff + hi * 8);
    const bf16x8 qf1 = *(const bf16x8*)(qg + qoff + 16 + hi * 8);

    f32x16 acc[8];
    #pragma unroll
    for (int n = 0; n < 8; ++n)
        #pragma unroll
        for (int r = 0; r < 16; ++r) acc[n][r] = 0.f;

    float lsum = 0.f;

    bf16x8 kA[2][2];
    #pragma unroll
    for (int s = 0; s < 2; ++s)
        #pragma unroll
        for (int st = 0; st < 2; ++st)
            kA[s][st] = *(const bf16x8*)(kg_bh + (size_t)(s * 32 + l31) * 32 + st * 16 + hi * 8);

    // prologue: stage tile 0 into xbuf0
    {
        const unsigned char* sp = x8b + (size_t)srow * 4096 + soff;
        uint4 la = *(const uint4*)sp;
        uint4 lb = *(const uint4*)(sp + 16);
        unsigned char* dp = xbuf0 + srow * 72 + soff;
        union { uint4 v; unsigned long long q[2]; } ua, ub;
        ua.v = la; ub.v = lb;
        ((unsigned long long*)dp)[0] = ua.q[0];
        ((unsigned long long*)dp)[1] = ua.q[1];
        ((unsigned long long*)(dp + 16))[0] = ub.q[0];
        ((unsigned long long*)(dp + 16))[1] = ub.q[1];
    }
    __syncthreads();

    for (int ut = 0; ut < 64; ++ut) {
        unsigned char* xcur = (ut & 1) ? xbuf1 : xbuf0;
        unsigned char* xnxt = (ut & 1) ? xbuf0 : xbuf1;

        // issue next-tile stage loads (wrap on last iter; write is harmless)
        const int u_next = ((ut + 1) & 63) * 64;
        const unsigned char* sp = x8b + (size_t)srow * 4096 + u_next + soff;
        const uint4 la = *(const uint4*)sp;
        const uint4 lb = *(const uint4*)(sp + 16);

        // ---- S^T = K * Q^T (bf16, log2-domain, scale pre-folded in Q) ----
        f32x16 s0 = MFMA32(kA[0][0], qf0, zf16());
        s0 = MFMA32(kA[0][1], qf1, s0);
        f32x16 s1 = MFMA32(kA[1][0], qf0, zf16());
        s1 = MFMA32(kA[1][1], qf1, s1);

        if (ut < 63) {  // prefetch next k-tile fragments
            const __bf16* kp = kg_bh + (size_t)(ut + 1) * 64 * 32;
            #pragma unroll
            for (int s = 0; s < 2; ++s)
                #pragma unroll
                for (int st = 0; st < 2; ++st)
                    kA[s][st] = *(const bf16x8*)(kp + (size_t)(s * 32 + l31) * 32 + st * 16 + hi * 8);
        }

        // ---- P = exp2(S); no max subtraction (bounded scores) ----
        float rs = 0.f;
        #pragma unroll
        for (int r = 0; r < 16; ++r) {
            float p = __builtin_amdgcn_exp2f(s0[r]);
            s0[r] = p; rs += p;
        }
        #pragma unroll
        for (int r = 0; r < 16; ++r) {
            float p = __builtin_amdgcn_exp2f(s1[r]);
            s1[r] = p; rs += p;
        }
        lsum += rs;

        // ---- P -> fp8 A-frags ----
        long pf0, pf1, pf2, pf3;
        MK8FRAG(pf0, s0, 0);
        MK8FRAG(pf1, s0, 8);
        MK8FRAG(pf2, s1, 0);
        MK8FRAG(pf3, s1, 8);

        // ---- PV (fp8): acc[n] += P[q][u16] * x[u16][d-tile n] ----
        __builtin_amdgcn_s_setprio(1);
        #pragma unroll
        for (int kk = 0; kk < 4; ++kk) {
            const long pa = (kk == 0) ? pf0 : (kk == 1) ? pf1 : (kk == 2) ? pf2 : pf3;
            #pragma unroll
            for (int n = 0; n < 8; ++n) {
                const long xb = *(const long*)(xcur + (n * 32 + l31) * 72 + kk * 16 + hi * 8);
                acc[n] = MFMA8(pa, xb, acc[n]);
            }
        }
        __builtin_amdgcn_s_setprio(0);

        // ---- write staged tile (compiler inserts vmcnt wait here) ----
        {
            unsigned char* dp = xnxt + srow * 72 + soff;
            union { uint4 v; unsigned long long q[2]; } ua, ub;
            ua.v = la; ub.v = lb;
            ((unsigned long long*)dp)[0] = ua.q[0];
            ((unsigned long long*)dp)[1] = ua.q[1];
            ((unsigned long long*)(dp + 16))[0] = ub.q[0];
            ((unsigned long long*)(dp + 16))[1] = ub.q[1];
        }
        __syncthreads();
    }

    // ---- epilogue: combine lsum across lane halves, broadcast 1/lsum ----
    lsum += __shfl_xor(lsum, 32);
    const float linv = 1.0f / lsum;
    if (!hi) scale_w[l31] = linv;
    f32x4 iv[4];
    #pragma unroll
    for (int q4 = 0; q4 < 4; ++q4)
        iv[q4] = *(const f32x4*)&scale_w[q4 * 8 + hi * 4];
    #pragma unroll
    for (int n = 0; n < 8; ++n) {
        #pragma unroll
        for (int r = 0; r < 16; ++r) {
            int t = t0 + w * 32 + (r & 3) + 8 * (r >> 2) + 4 * hi;
            int d = n * 32 + l31;
            ctx[((size_t)(b * 4096 + t) * 8 + h) * 256 + d] =
                (__bf16)(acc[n][r] * iv[r >> 2][r & 3]);
        }
    }
}

// ---------------------------------------------------------------------------
// gemm_out (round-8): out[bt][e] = sum_k ctx[bt][k] * VOT[e][k].
// block = 64 m-rows x 128 e (4 waves; wave = 2 m-tiles x 32 e).
// ---------------------------------------------------------------------------
__global__ __launch_bounds__(256) void gemm_out(const __bf16* __restrict__ ctx,
                                                const __bf16* __restrict__ vot,
                                                float* __restrict__ out) {
    const int bid = blockIdx.x;
    const int mt2 = bid >> 1;
    const int eh = bid & 1;
    const int w = threadIdx.x >> 6;
    const int l = threadIdx.x & 63;
    const int l31 = l & 31, hi = l >> 5;
    const size_t a0row = (size_t)(mt2 * 64 + l31) * 2048;
    const size_t a1row = (size_t)(mt2 * 64 + 32 + l31) * 2048;
    const size_t brow  = (size_t)(eh * 128 + w * 32 + l31) * 2048;
    f32x16 acc0 = zf16(), acc1 = zf16();
    #pragma unroll 4
    for (int kk = 0; kk < 128; ++kk) {
        bf16x8 bfr = *(const bf16x8*)(vot + brow + kk * 16 + hi * 8);
        bf16x8 a0  = *(const bf16x8*)(ctx + a0row + kk * 16 + hi * 8);
        bf16x8 a1  = *(const bf16x8*)(ctx + a1row + kk * 16 + hi * 8);
        acc0 = MFMA32(a0, bfr, acc0);
        acc1 = MFMA32(a1, bfr, acc1);
    }
    const int e = eh * 128 + w * 32 + l31;
    #pragma unroll
    for (int r = 0; r < 16; ++r) {
        int crow = (r & 3) + 8 * (r >> 2) + 4 * hi;
        out[(size_t)(mt2 * 64 + crow) * 256 + e]      = acc0[r];
        out[(size_t)(mt2 * 64 + 32 + crow) * 256 + e] = acc1[r];
    }
}

// ---------------------------------------------------------------------------
extern "C" void kernel_launch(void* const* d_in, const int* in_sizes, int n_in,
                              void* d_out, int out_size, void* d_ws, size_t ws_size,
                              hipStream_t stream) {
    const float* x  = (const float*)d_in[0];  // [2][4096][256]
    const float* Qw = (const float*)d_in[1];  // [8][32][256]
    const float* Kw = (const float*)d_in[2];  // [8][32][256]
    const float* VO = (const float*)d_in[3];  // [8][256][256]
    float* out = (float*)d_out;               // [2][4096][256]

    char* ws = (char*)d_ws;
    unsigned char* x8 = (unsigned char*)(ws);              // 2 MB  [2][256][4096] fp8
    __bf16* xrow = (__bf16*)(ws + ((size_t)4 << 20));      // 4 MB  [2][4096][256]
    __bf16* qb   = (__bf16*)(ws + ((size_t)8 << 20));      // 4 MB  [2][8][4096][32]
    __bf16* kb   = (__bf16*)(ws + ((size_t)12 << 20));     // 4 MB
    __bf16* wb   = (__bf16*)(ws + ((size_t)16 << 20));     // 256 KB [2][8][32][256]
    __bf16* vot  = (__bf16*)(ws + ((size_t)17 << 20));     // 1 MB  [256][2048]
    __bf16* ctx  = (__bf16*)(ws + ((size_t)18 << 20));     // 32 MB [2][4096][8][256]

    prep<<<896, 256, 0, stream>>>(x, Qw, Kw, VO, x8, xrow, wb, vot);
    proj_kernel<<<128, 256, 0, stream>>>(xrow, wb, qb, kb);
    attn_kernel<<<256, 512, 0, stream>>>(qb, kb, x8, ctx);
    gemm_out<<<256, 256, 0, stream>>>(ctx, vot, out);
}